// Round 9
// baseline (288.652 us; speedup 1.0000x reference)
//
#include <hip/hip_runtime.h>
#include <hip/hip_cooperative_groups.h>

namespace cg = cooperative_groups;

typedef __bf16 bf16x8 __attribute__((ext_vector_type(8)));
typedef float f32x4 __attribute__((ext_vector_type(4)));
typedef unsigned short u16;
typedef unsigned short u16x4 __attribute__((ext_vector_type(4)));
typedef unsigned short u16x8 __attribute__((ext_vector_type(8)));

#define MFMA16(a, b, c) __builtin_amdgcn_mfma_f32_16x16x32_bf16(a, b, c, 0, 0, 0)

__device__ __forceinline__ u16 f2bf(float f) {
    unsigned u = __builtin_bit_cast(unsigned, f);
    u += 0x7fffu + ((u >> 16) & 1u);   // RNE
    return (u16)(u >> 16);
}

__device__ __forceinline__ bf16x8 ld_frag(const u16* p) {
    u16x8 v = *(const u16x8*)p;
    return __builtin_bit_cast(bf16x8, v);
}

__device__ __forceinline__ u16x8 pack8(float4 a, float4 b) {
    u16x8 o = { f2bf(a.x), f2bf(a.y), f2bf(a.z), f2bf(a.w),
                f2bf(b.x), f2bf(b.y), f2bf(b.z), f2bf(b.w) };
    return o;
}

__device__ __forceinline__ bf16x8 cvt8(float4 a, float4 b) {
    return __builtin_bit_cast(bf16x8, pack8(a, b));
}

// async global->LDS, 16B/lane; LDS dest = wave-uniform base + lane*16
__device__ __forceinline__ void glds16(const void* g, void* l) {
    __builtin_amdgcn_global_load_lds(
        (const __attribute__((address_space(1))) unsigned int*)g,
        (__attribute__((address_space(3))) unsigned int*)l, 16, 0, 0);
}

// ---------------------------------------------------------------------------
// ONE cooperative kernel, grid 256 x 512 (1 block/CU, co-resident).
// Phase 0: wcvt  W fp32 -> Wb bf16 frag-order      (R8-verified layout)
// Phase 1: qkv   q|k|v = x@W^T+b; x read once; A reg-path, B glds16 dbuf
// Phase 2: kt_v  partial T[e][d] per 128-t chunk, e-halved (256 units)
// Phase 3: reduce 32 partials -> T bf16 (scale folded)
// Phase 4: out   outT-form GEMM, f32x4 full-line stores
// ---------------------------------------------------------------------------
__global__ __launch_bounds__(512, 2) void fused(
    const float* __restrict__ x,
    const float* __restrict__ Wq, const float* __restrict__ bq,
    const float* __restrict__ Wk, const float* __restrict__ bk,
    const float* __restrict__ Wv, const float* __restrict__ bv,
    u16* __restrict__ Wb, u16* __restrict__ qo,
    u16* __restrict__ kT, u16* __restrict__ vT,
    float* __restrict__ part, u16* __restrict__ T,
    float* __restrict__ out)
{
    __shared__ __align__(16) u16 smem[26112];   // 51 KB pool, phase-aliased

    cg::grid_group grid = cg::this_grid();

    const int bid = blockIdx.x;
    const int tid = threadIdx.x, lane = tid & 63, w = tid >> 6;
    const int quad = lane >> 4, l16 = lane & 15;

    // ================= Phase 0: wcvt =================
    // Wb u16 off = ((cc*24 + n16)*64 + lane)*8 ; elem = Wcat[n16*16+l16][cc*32+quad*8+j]
    {
        int g = bid * 512 + tid;
        if (g < 49152) {
            int gl16 = g & 15, gquad = (g >> 4) & 3;
            int n16 = (g >> 6) % 24;
            int cc  = (g >> 6) / 24;
            int nrow = n16 * 16 + gl16;
            int nt = nrow >> 7, r = nrow & 127;
            int col = cc * 32 + gquad * 8;
            const float* W = (nt == 0 ? Wq : nt == 1 ? Wk : Wv) + (size_t)r * 1024 + col;
            float4 a = *(const float4*)(W);
            float4 b = *(const float4*)(W + 4);
            *(u16x8*)(Wb + (size_t)g * 8) = pack8(a, b);
        }
    }
    grid.sync();

    // ================= Phase 1: qkv =================
    {
        const int m0 = bid * 64;
        const int wm32 = w & 1;          // m-half (32 rows)
        const int wn16 = (w >> 1) * 6;   // first n16 frag (6 x 16 = 96 cols)

        // A: per-lane global x (no LDS); rows shared by the 4 n-waves via L1
        const float* xrow0 = x + (size_t)(m0 + wm32 * 32 + l16) * 1024 + quad * 8;
        const float* xrow1 = xrow0 + (size_t)16 * 1024;

        // B: wave w glds-copies frags w*3..w*3+2; dbuf at smem[0]/smem[12288]
        const u16* wb0 = Wb + (w * 3) * 512 + lane * 8;

        f32x4 acc[2][6] = {};

        // prologue: B chunk 0 -> buf0; x chunk 0 -> regs
        #pragma unroll
        for (int j = 0; j < 3; ++j)
            glds16(wb0 + j * 512, &smem[(w * 3 + j) * 512]);
        float4 x0a = *(const float4*)(xrow0);
        float4 x0b = *(const float4*)(xrow0 + 4);
        float4 x1a = *(const float4*)(xrow1);
        float4 x1b = *(const float4*)(xrow1 + 4);

        for (int c = 0; c < 32; ++c) {
            const int cur = c & 1, nxt = cur ^ 1;
            __syncthreads();   // buf[cur] staged (vmcnt drained at barrier)

            float4 n0a, n0b, n1a, n1b;
            if (c < 31) {      // prefetch chunk c+1
                const u16* wbn = wb0 + (size_t)(c + 1) * 12288;
                u16* Bn = &smem[nxt * 12288];
                #pragma unroll
                for (int j = 0; j < 3; ++j)
                    glds16(wbn + j * 512, &Bn[(w * 3 + j) * 512]);
                n0a = *(const float4*)(xrow0 + (c + 1) * 32);
                n0b = *(const float4*)(xrow0 + (c + 1) * 32 + 4);
                n1a = *(const float4*)(xrow1 + (c + 1) * 32);
                n1b = *(const float4*)(xrow1 + (c + 1) * 32 + 4);
            }

            bf16x8 af[2];
            af[0] = cvt8(x0a, x0b);
            af[1] = cvt8(x1a, x1b);
            const u16* Bc = &smem[cur * 12288];
            bf16x8 bfr[6];
            #pragma unroll
            for (int ni = 0; ni < 6; ++ni)
                bfr[ni] = ld_frag(&Bc[(wn16 + ni) * 512 + lane * 8]);
            #pragma unroll
            for (int mi = 0; mi < 2; ++mi)
                #pragma unroll
                for (int ni = 0; ni < 6; ++ni)
                    acc[mi][ni] = MFMA16(af[mi], bfr[ni], acc[mi][ni]);

            if (c < 31) {
                x0a = n0a; x0b = n0b; x1a = n1a; x1b = n1b;
            }
        }

        // epilogue A: q natural via Eq[64][136]
        __syncthreads();
        u16* Eq = smem;
        #pragma unroll
        for (int ni = 0; ni < 6; ++ni) {
            int n16g = wn16 + ni;
            if (n16g < 8) {
                int col = n16g * 16 + l16;
                float bb = bq[col];
                #pragma unroll
                for (int mi = 0; mi < 2; ++mi)
                    #pragma unroll
                    for (int r = 0; r < 4; ++r)
                        Eq[(wm32 * 32 + mi * 16 + quad * 4 + r) * 136 + col] =
                            f2bf(acc[mi][ni][r] + bb);
            }
        }
        __syncthreads();
        #pragma unroll
        for (int i = 0; i < 2; ++i) {
            int idx = tid + i * 512;
            int row = idx >> 4, d8 = (idx & 15) * 8;
            *(u16x8*)(qo + (size_t)(m0 + row) * 128 + d8) = *(u16x8*)&Eq[row * 136 + d8];
        }

        // epilogue B: k,v transposed via Ek/Ev[128][72]
        __syncthreads();
        u16* Ek = smem;
        u16* Ev = smem + 9216;
        #pragma unroll
        for (int ni = 0; ni < 6; ++ni) {
            int n16g = wn16 + ni;
            if (n16g >= 8) {
                int col = (n16g & 7) * 16 + l16;
                const float* bias = (n16g < 16) ? bk : bv;
                u16* E = (n16g < 16) ? Ek : Ev;
                float bb = bias[col];
                #pragma unroll
                for (int mi = 0; mi < 2; ++mi) {
                    u16x4 v4 = { f2bf(acc[mi][ni][0] + bb), f2bf(acc[mi][ni][1] + bb),
                                 f2bf(acc[mi][ni][2] + bb), f2bf(acc[mi][ni][3] + bb) };
                    *(u16x4*)&E[col * 72 + wm32 * 32 + mi * 16 + quad * 4] = v4;
                }
            }
        }
        __syncthreads();
        #pragma unroll
        for (int i = 0; i < 2; ++i) {
            int idx = tid + i * 512;
            int d = idx >> 3, t8 = (idx & 7) * 8;
            *(u16x8*)(kT + (size_t)d * 16384 + m0 + t8) = *(u16x8*)&Ek[d * 72 + t8];
            *(u16x8*)(vT + (size_t)d * 16384 + m0 + t8) = *(u16x8*)&Ev[d * 72 + t8];
        }
    }
    grid.sync();

    // ================= Phase 2: kt_v (256 units: b x chunk x e-half) ========
    {
        const int b  = bid >> 6;
        const int cc = (bid >> 1) & 31;
        const int eh = bid & 1;
        const size_t g0 = (size_t)b * 4096 + cc * 128;

        u16* kL = smem;            // 128 x 136
        u16* vL = smem + 17408;    //  64 x 136
        __syncthreads();
        #pragma unroll
        for (int i = 0; i < 4; ++i) {
            int idx = tid + i * 512;
            int d = idx >> 4, t8 = (idx & 15) * 8;
            *(u16x8*)&kL[d * 136 + t8] = *(const u16x8*)(kT + (size_t)d * 16384 + g0 + t8);
        }
        #pragma unroll
        for (int i = 0; i < 2; ++i) {
            int idx = tid + i * 512;
            int e = idx >> 4, t8 = (idx & 15) * 8;
            *(u16x8*)&vL[e * 136 + t8] =
                *(const u16x8*)(vT + (size_t)(eh * 64 + e) * 16384 + g0 + t8);
        }
        __syncthreads();

        const int we2 = (w >> 2) * 32, wd = (w & 3) * 32;
        f32x4 acc[2][2] = {};
        #pragma unroll
        for (int ks = 0; ks < 4; ++ks) {
            bf16x8 af[2], bfr[2];
            #pragma unroll
            for (int mi = 0; mi < 2; ++mi)
                af[mi] = ld_frag(&vL[(we2 + mi * 16 + l16) * 136 + ks * 32 + quad * 8]);
            #pragma unroll
            for (int ni = 0; ni < 2; ++ni)
                bfr[ni] = ld_frag(&kL[(wd + ni * 16 + l16) * 136 + ks * 32 + quad * 8]);
            #pragma unroll
            for (int mi = 0; mi < 2; ++mi)
                #pragma unroll
                for (int ni = 0; ni < 2; ++ni)
                    acc[mi][ni] = MFMA16(af[mi], bfr[ni], acc[mi][ni]);
        }

        float* dst = part + (size_t)(b * 32 + cc) * 16384;
        #pragma unroll
        for (int mi = 0; mi < 2; ++mi)
            #pragma unroll
            for (int ni = 0; ni < 2; ++ni)
                #pragma unroll
                for (int r = 0; r < 4; ++r)
                    dst[(eh * 64 + we2 + mi * 16 + quad * 4 + r) * 128 +
                        (wd + ni * 16 + l16)] = acc[mi][ni][r];
    }
    grid.sync();

    // ================= Phase 3: reduce 32 partials -> T bf16 ================
    {
        if (tid < 256) {
            int elem = bid * 256 + tid;            // 0..65535
            int b = elem >> 14, idx = elem & 16383;
            const float* p = part + (size_t)b * 32 * 16384 + idx;
            float s = 0.f;
            #pragma unroll
            for (int c = 0; c < 32; ++c) s += p[(size_t)c * 16384];
            T[elem] = f2bf(s * 0.088388347648318447f);   // 128^-0.5
        }
    }
    grid.sync();

    // ================= Phase 4: out GEMM (s-tile 64) ========================
    {
        const int s0 = bid * 64;
        const int b  = s0 >> 12;

        u16* tL = smem;            // 128 x 136
        u16* qL = smem + 17408;    //  64 x 136
        __syncthreads();
        #pragma unroll
        for (int i = 0; i < 4; ++i) {
            int idx = tid + i * 512;
            int e = idx >> 4, d8 = (idx & 15) * 8;
            *(u16x8*)&tL[e * 136 + d8] =
                *(const u16x8*)(T + (size_t)b * 16384 + e * 128 + d8);
        }
        #pragma unroll
        for (int i = 0; i < 2; ++i) {
            int idx = tid + i * 512;
            int sr = idx >> 4, d8 = (idx & 15) * 8;
            *(u16x8*)&qL[sr * 136 + d8] =
                *(const u16x8*)(qo + (size_t)(s0 + sr) * 128 + d8);
        }
        __syncthreads();

        const int we = (w >> 2) * 64, wsx = (w & 3) * 16;
        f32x4 acc[4] = {};
        #pragma unroll
        for (int ks = 0; ks < 4; ++ks) {
            bf16x8 bfr = ld_frag(&qL[(wsx + l16) * 136 + ks * 32 + quad * 8]);
            #pragma unroll
            for (int mi = 0; mi < 4; ++mi) {
                bf16x8 af = ld_frag(&tL[(we + mi * 16 + l16) * 136 + ks * 32 + quad * 8]);
                acc[mi] = MFMA16(af, bfr, acc[mi]);
            }
        }
        #pragma unroll
        for (int mi = 0; mi < 4; ++mi) {
            int s = s0 + wsx + l16;
            int e0 = we + mi * 16 + quad * 4;
            *(f32x4*)(out + (size_t)s * 128 + e0) = acc[mi];
        }
    }
}

// ---------------------------------------------------------------------------
extern "C" void kernel_launch(void* const* d_in, const int* in_sizes, int n_in,
                              void* d_out, int out_size, void* d_ws, size_t ws_size,
                              hipStream_t stream)
{
    const float* x  = (const float*)d_in[0];
    const float* Wq = (const float*)d_in[1];
    const float* bq = (const float*)d_in[2];
    const float* Wk = (const float*)d_in[3];
    const float* bk = (const float*)d_in[4];
    const float* Wv = (const float*)d_in[5];
    const float* bv = (const float*)d_in[6];
    float* out = (float*)d_out;

    char* ws = (char*)d_ws;
    u16*   qo   = (u16*)(ws);                          //  4 MB, [s][d]
    u16*   kT   = (u16*)(ws + ((size_t)4 << 20));      //  4 MB, [d][t]
    u16*   vT   = (u16*)(ws + ((size_t)8 << 20));      //  4 MB, [e][t]
    // Wb (768 KB) aliases part (8 MB): Wb dead before phase 2 writes part.
    u16*   Wb   = (u16*)(ws + ((size_t)12 << 20));
    float* part = (float*)(ws + ((size_t)12 << 20));
    u16*   T    = (u16*)(ws + ((size_t)20 << 20));     // 128 KB

    void* args[] = { &x, &Wq, &bq, &Wk, &bk, &Wv, &bv,
                     &Wb, &qo, &kT, &vT, &part, &T, &out };
    hipLaunchCooperativeKernel((const void*)fused, dim3(256), dim3(512),
                               args, 0, stream);
}